// Round 1
// 407.646 us; speedup vs baseline: 1.3452x; 1.3452x over previous
//
#include <hip/hip_runtime.h>
#include <cstdint>
#include <cstddef>

typedef __attribute__((ext_vector_type(8))) short short8;
typedef __attribute__((ext_vector_type(4))) float f32x4;

#define EPSF 1e-5f

__device__ __forceinline__ unsigned short f2bf(float f) {
  union { float f; unsigned u; } v; v.f = f;
  unsigned r = v.u + 0x7FFFu + ((v.u >> 16) & 1u);
  return (unsigned short)(r >> 16);
}

// ---------------------------------------------------------------- kernel A
// per (b,c): sf = mean_t, tf = mean_v, and g1vt[b][c][v][t] = bf16(g1[b][c][t][v])
__global__ __launch_bounds__(256) void k_means_tr(
    const float* __restrict__ g1, float* __restrict__ sf, float* __restrict__ tf,
    unsigned short* __restrict__ g1vt) {
  __shared__ __align__(16) float tile[1600];
  int bc = blockIdx.x;
  const float4* src = (const float4*)(g1 + (size_t)bc * 1600);
  float4* dst = (float4*)tile;
  for (int i = threadIdx.x; i < 400; i += 256) dst[i] = src[i];
  __syncthreads();
  int t = threadIdx.x;
  if (t < 64) {
    float s = 0.f;
    #pragma unroll
    for (int v = 0; v < 25; ++v) s += tile[t * 25 + v];
    tf[(size_t)bc * 64 + t] = s * (1.f / 25.f);
  } else if (t < 89) {
    int v = t - 64;
    float s = 0.f;
    for (int tt = 0; tt < 64; ++tt) s += tile[tt * 25 + v];
    sf[(size_t)bc * 25 + v] = s * (1.f / 64.f);
  }
  for (int p = threadIdx.x; p < 800; p += 256) {
    int j = p * 2;
    int v = j >> 6, tt = j & 63;
    unsigned short lo = f2bf(tile[tt * 25 + v]);
    unsigned short hi = f2bf(tile[(tt + 1) * 25 + v]);
    unsigned pack = (unsigned)lo | ((unsigned)hi << 16);
    *((unsigned*)(g1vt + (size_t)bc * 1600 + j)) = pack;
  }
}

// ---------------------------------------------------------------- kernel B (spatial attn)
__global__ __launch_bounds__(256) void k_spat(
    const float* __restrict__ sf, const float* __restrict__ sc1_w, const float* __restrict__ sc1_b,
    const float* __restrict__ sc2_w, const float* __restrict__ sc2_b,
    const float* __restrict__ As_r, const float* __restrict__ act_s,
    float* __restrict__ As_ws, float* __restrict__ out_As_at, float* __restrict__ out_As_act) {
  __shared__ float sfl[3200], w1[2048], w2[2048], s1[400], s2[400];
  int b = blockIdx.x;
  for (int i = threadIdx.x; i < 3200; i += 256) sfl[i] = sf[(size_t)b * 3200 + i];
  for (int i = threadIdx.x; i < 2048; i += 256) { w1[i] = sc1_w[i]; w2[i] = sc2_w[i]; }
  __syncthreads();
  for (int i = threadIdx.x; i < 800; i += 256) {
    if (i < 400) {
      int v = i >> 4, r = i & 15;
      float s = sc1_b[r];
      for (int c = 0; c < 128; ++c) s += w1[r * 128 + c] * sfl[c * 25 + v];
      s1[v * 16 + r] = s;
    } else {
      int j = i - 400;
      int r = j / 25, u = j % 25;
      float s = sc2_b[r];
      for (int c = 0; c < 128; ++c) s += w2[r * 128 + c] * sfl[c * 25 + u];
      s2[r * 25 + u] = s;
    }
  }
  __syncthreads();
  for (int i = threadIdx.x; i < 625; i += 256) {
    int v = i / 25, u = i % 25;
    float d = 0.f;
    #pragma unroll
    for (int r = 0; r < 16; ++r) d += s1[v * 16 + r] * s2[r * 25 + u];
    float at = d > 0.f ? tanhf(d) : 0.f;
    float act = As_r[(size_t)b * 625 + i] * act_s[i];
    out_As_at[(size_t)b * 625 + i] = at;
    out_As_act[(size_t)b * 625 + i] = act;
    As_ws[(size_t)b * 625 + i] = at + act;
  }
}

// ---------------------------------------------------------------- kernel C (temporal attn)
__global__ __launch_bounds__(256) void k_temp(
    const float* __restrict__ tf, const float* __restrict__ tc1_w, const float* __restrict__ tc1_b,
    const float* __restrict__ tc2_w, const float* __restrict__ tc2_b,
    const float* __restrict__ At_r, const float* __restrict__ act_t,
    float* __restrict__ Atev_ws, float* __restrict__ out_At_at, float* __restrict__ out_At_act) {
  __shared__ float tfl[8192], w1[2048], w2[2048], t1[1024], t2[1024];
  int b = blockIdx.x;
  for (int i = threadIdx.x; i < 8192; i += 256) tfl[i] = tf[(size_t)b * 8192 + i];
  for (int i = threadIdx.x; i < 2048; i += 256) { w1[i] = tc1_w[i]; w2[i] = tc2_w[i]; }
  __syncthreads();
  for (int i = threadIdx.x; i < 2048; i += 256) {
    if (i < 1024) {
      int t = i >> 4, r = i & 15;
      float s = tc1_b[r];
      for (int c = 0; c < 128; ++c) s += w1[r * 128 + c] * tfl[c * 64 + t];
      t1[t * 16 + r] = s;
    } else {
      int j = i - 1024;
      int r = j >> 6, t = j & 63;
      float s = tc2_b[r];
      for (int c = 0; c < 128; ++c) s += w2[r * 128 + c] * tfl[c * 64 + t];
      t2[r * 64 + t] = s;
    }
  }
  __syncthreads();
  for (int i = threadIdx.x; i < 4096; i += 256) {
    int t = i >> 6, y = i & 63;
    float d = 0.f;
    #pragma unroll
    for (int r = 0; r < 16; ++r) d += t1[t * 16 + r] * t2[r * 64 + y];
    float at = d > 0.f ? tanhf(d) : 0.f;
    float act = At_r[(size_t)b * 4096 + i] * act_t[i];
    out_At_at[(size_t)b * 4096 + i] = at;
    out_At_act[(size_t)b * 4096 + i] = act;
    if ((y & 1) == 0)
      Atev_ws[(size_t)b * 2048 + (y >> 1) * 64 + t] = at + act;  // At_ev[b][y/2][t] = At[b][t][y]
  }
}

// ---------------------------------------------------------------- kernel P (fold sp+bn into W1/W2)
__global__ __launch_bounds__(256) void k_prep(
    const float* __restrict__ W1_w, const float* __restrict__ W1_b,
    const float* __restrict__ W2_w, const float* __restrict__ W2_b,
    const float* __restrict__ sp_w, const float* __restrict__ sp_b,
    const float* __restrict__ sp_gamma, const float* __restrict__ sp_beta,
    const float* __restrict__ sp_mean, const float* __restrict__ sp_var,
    const float* __restrict__ bn_gamma, const float* __restrict__ bn_beta,
    const float* __restrict__ bn_mean, const float* __restrict__ bn_var,
    unsigned short* __restrict__ Wc1, unsigned short* __restrict__ Wc2,
    float* __restrict__ b1p, float* __restrict__ b2p,
    float* __restrict__ bnsc, float* __restrict__ bnsh) {
  __shared__ float w1row[256], w2row[256], scale[128], shift[128];
  int o = blockIdx.x;
  int t = threadIdx.x;
  w1row[t] = W1_w[o * 256 + t];
  w2row[t] = W2_w[o * 256 + t];
  if (t < 128) {
    float sc = sp_gamma[t] * rsqrtf(sp_var[t] + EPSF);
    scale[t] = sc;
    shift[t] = (sp_b[t] - sp_mean[t]) * sc + sp_beta[t];
  }
  __syncthreads();
  if (t < 128) {
    float a1 = 0.f, a2 = 0.f;
    for (int c = 0; c < 128; ++c) {
      float sw = sp_w[c * 128 + t];
      a1 += w1row[c] * scale[c] * sw;
      a2 += w2row[c] * scale[c] * sw;
    }
    Wc1[o * 256 + t] = f2bf(a1);
    Wc2[o * 256 + t] = f2bf(a2);
  } else {
    Wc1[o * 256 + t] = f2bf(w1row[t]);
    Wc2[o * 256 + t] = f2bf(w2row[t]);
  }
  if (t == 0) {
    float s = 0.f;
    for (int c = 0; c < 128; ++c) s += w1row[c] * shift[c];
    b1p[o] = W1_b[o] + s;
    float bs = bn_gamma[o] * rsqrtf(bn_var[o] + EPSF);
    bnsc[o] = bs;
    bnsh[o] = bn_beta[o] - bn_mean[o] * bs;
  } else if (t == 1) {
    float s = 0.f;
    for (int c = 0; c < 128; ++c) s += w2row[c] * shift[c];
    b2p[o] = W2_b[o] + s;
  }
}

// ---------------------------------------------------------------- kernel N (nu2 via 2-stage MFMA)
// per block: b, 8 channels. stage1: P2[y][(c,v)] = At_ev @ g1vt; stage2: nu2[c][y][u] = P2 @ As^T
__global__ __launch_bounds__(256) void k_nu2(
    const unsigned short* __restrict__ g1vt, const float* __restrict__ Atev,
    const float* __restrict__ As_ws, unsigned short* __restrict__ nu2) {
  __shared__ __align__(16) unsigned short At_l[32 * 72];   // [y][t] pad 72
  __shared__ __align__(16) unsigned short As_l[32 * 40];   // [u][v] pad 40, zero-padded
  __shared__ __align__(16) unsigned short P2_l[8 * 32 * 40]; // [c][y][v] pad 40
  int blk = blockIdx.x;
  int b = blk >> 4;
  int c0 = (blk & 15) * 8;
  int tid = threadIdx.x;
  int w = tid >> 6, l = tid & 63;
  for (int i = tid; i < 2048; i += 256)
    At_l[(i >> 6) * 72 + (i & 63)] = f2bf(Atev[(size_t)b * 2048 + i]);
  for (int i = tid; i < 1280; i += 256) As_l[i] = 0;
  for (int i = tid; i < 10240; i += 256) P2_l[i] = 0;
  __syncthreads();
  for (int i = tid; i < 625; i += 256)
    As_l[(i / 25) * 40 + (i % 25)] = f2bf(As_ws[(size_t)b * 625 + i]);
  __syncthreads();

  // stage 1: A-frags (At) preloaded
  short8 afr[2][2];
  #pragma unroll
  for (int mi = 0; mi < 2; ++mi)
    #pragma unroll
    for (int ks = 0; ks < 2; ++ks) {
      int y = mi * 16 + (l & 15);
      int tt = ks * 32 + (l >> 4) * 8;
      afr[mi][ks] = *(const short8*)(At_l + y * 72 + tt);
    }
  for (int nt = w; nt < 13; nt += 4) {
    int n = nt * 16 + (l & 15);
    int nc = n < 200 ? n : 199;
    int cc = nc / 25, vv = nc % 25;
    const unsigned short* gp = g1vt + ((size_t)(b * 128 + c0 + cc) * 25 + vv) * 64;
    short8 bfr[2];
    #pragma unroll
    for (int ks = 0; ks < 2; ++ks)
      bfr[ks] = *(const short8*)(gp + ks * 32 + (l >> 4) * 8);
    #pragma unroll
    for (int mi = 0; mi < 2; ++mi) {
      f32x4 acc = {0.f, 0.f, 0.f, 0.f};
      acc = __builtin_amdgcn_mfma_f32_16x16x32_bf16(afr[mi][0], bfr[0], acc, 0, 0, 0);
      acc = __builtin_amdgcn_mfma_f32_16x16x32_bf16(afr[mi][1], bfr[1], acc, 0, 0, 0);
      if (n < 200) {
        #pragma unroll
        for (int r = 0; r < 4; ++r) {
          int y = mi * 16 + (l >> 4) * 4 + r;
          P2_l[cc * 1280 + y * 40 + vv] = f2bf(acc[r]);
        }
      }
    }
  }
  __syncthreads();

  // stage 2
  for (int cw = w; cw < 8; cw += 4) {
    #pragma unroll
    for (int mi = 0; mi < 2; ++mi) {
      int y = mi * 16 + (l & 15);
      short8 a2 = *(const short8*)(P2_l + cw * 1280 + y * 40 + (l >> 4) * 8);
      #pragma unroll
      for (int nt2 = 0; nt2 < 2; ++nt2) {
        int u = nt2 * 16 + (l & 15);
        short8 b2 = *(const short8*)(As_l + u * 40 + (l >> 4) * 8);
        f32x4 acc = {0.f, 0.f, 0.f, 0.f};
        acc = __builtin_amdgcn_mfma_f32_16x16x32_bf16(a2, b2, acc, 0, 0, 0);
        #pragma unroll
        for (int r = 0; r < 4; ++r) {
          int yy = mi * 16 + (l >> 4) * 4 + r;
          int uu = nt2 * 16 + (l & 15);
          if (uu < 25)
            nu2[(size_t)(b * 128 + c0 + cw) * 800 + yy * 25 + uu] = f2bf(acc[r]);
        }
      }
    }
  }
}

// ---------------------------------------------------------------- kernel F (final GLU GEMM + bn)
// v2: 512 threads / 8 waves; wave w owns o-rows [32w,32w+32) with BOTH weight matrices
// held in registers for the whole block. Block covers 160 positions = 5 subtiles of 32;
// next subtile's X (nu2 bf16 + h2 f32) is prefetched into registers during compute (T14).
__global__ __launch_bounds__(512) void k_final(
    const unsigned short* __restrict__ nu2, const float* __restrict__ h2,
    const unsigned short* __restrict__ Wc1, const unsigned short* __restrict__ Wc2,
    const float* __restrict__ b1p, const float* __restrict__ b2p,
    const float* __restrict__ bnsc, const float* __restrict__ bnsh,
    float* __restrict__ g2) {
  __shared__ __align__(16) unsigned short x_l[32 * 264];  // [p][k] pad 264 (2-way-free on b128 reads)
  int blk = blockIdx.x;
  int b = blk / 5;
  int pbase = (blk % 5) * 160;
  int tid = threadIdx.x;
  int w = tid >> 6, l = tid & 63;
  int lrow = l & 15, lgr = l >> 4;
  int ow0 = w * 32;

  // ---- weights into registers: 2 mi x 8 ks x 2 mats = 32 short8 = 128 VGPR
  short8 aw1[2][8], aw2[2][8];
  {
    const unsigned short* wr1 = Wc1 + (ow0 + lrow) * 256 + lgr * 8;
    const unsigned short* wr2 = Wc2 + (ow0 + lrow) * 256 + lgr * 8;
    #pragma unroll
    for (int mi = 0; mi < 2; ++mi)
      #pragma unroll
      for (int ks = 0; ks < 8; ++ks) {
        aw1[mi][ks] = *(const short8*)(wr1 + mi * 16 * 256 + ks * 32);
        aw2[mi][ks] = *(const short8*)(wr2 + mi * 16 * 256 + ks * 32);
      }
  }
  // ---- per-lane epilogue constants
  float b1v[2][4], b2v[2][4], scv[2][4], shv[2][4];
  #pragma unroll
  for (int mi = 0; mi < 2; ++mi)
    #pragma unroll
    for (int r = 0; r < 4; ++r) {
      int o = ow0 + mi * 16 + lgr * 4 + r;
      b1v[mi][r] = b1p[o];
      b2v[mi][r] = b2p[o];
      scv[mi][r] = bnsc[o];
      shv[mi][r] = bnsh[o];
    }

  // staging assignment: thread handles one nu2 chunk (8 bf16) and one h2 chunk (8 f32)
  int kA = tid >> 2;        // 0..127
  int pA = (tid & 3) * 8;   // 0,8,16,24
  const unsigned short* srcA = nu2 + ((size_t)b * 128 + kA) * 800 + pbase + pA;
  const float* srcB = h2 + ((size_t)b * 128 + kA) * 800 + pbase + pA;

  short8 cA;
  float4 cB0, cB1;
  // prologue: load subtile 0 into registers
  cA = *(const short8*)srcA;
  cB0 = *(const float4*)srcB;
  cB1 = *(const float4*)(srcB + 4);

  for (int pt = 0; pt < 5; ++pt) {
    // write staged registers into LDS (transpose: [p][k])
    #pragma unroll
    for (int j = 0; j < 8; ++j)
      x_l[(pA + j) * 264 + kA] = (unsigned short)cA[j];
    x_l[(pA + 0) * 264 + 128 + kA] = f2bf(cB0.x);
    x_l[(pA + 1) * 264 + 128 + kA] = f2bf(cB0.y);
    x_l[(pA + 2) * 264 + 128 + kA] = f2bf(cB0.z);
    x_l[(pA + 3) * 264 + 128 + kA] = f2bf(cB0.w);
    x_l[(pA + 4) * 264 + 128 + kA] = f2bf(cB1.x);
    x_l[(pA + 5) * 264 + 128 + kA] = f2bf(cB1.y);
    x_l[(pA + 6) * 264 + 128 + kA] = f2bf(cB1.z);
    x_l[(pA + 7) * 264 + 128 + kA] = f2bf(cB1.w);
    __syncthreads();

    // T14: issue next subtile's global loads before compute — latency hides under MFMA
    if (pt < 4) {
      cA = *(const short8*)(srcA + (pt + 1) * 32);
      cB0 = *(const float4*)(srcB + (pt + 1) * 32);
      cB1 = *(const float4*)(srcB + (pt + 1) * 32 + 4);
    }

    // compute: 2 mi x 2 nf x 8 ks x 2 mats = 64 MFMA per wave
    f32x4 vz = {0.f, 0.f, 0.f, 0.f};
    f32x4 acc1[2][2], acc2[2][2];
    #pragma unroll
    for (int mi = 0; mi < 2; ++mi)
      #pragma unroll
      for (int nf = 0; nf < 2; ++nf) { acc1[mi][nf] = vz; acc2[mi][nf] = vz; }
    #pragma unroll
    for (int ks = 0; ks < 8; ++ks) {
      int koff = ks * 32 + lgr * 8;
      short8 bf0 = *(const short8*)(x_l + lrow * 264 + koff);
      short8 bf1 = *(const short8*)(x_l + (16 + lrow) * 264 + koff);
      acc1[0][0] = __builtin_amdgcn_mfma_f32_16x16x32_bf16(aw1[0][ks], bf0, acc1[0][0], 0, 0, 0);
      acc1[0][1] = __builtin_amdgcn_mfma_f32_16x16x32_bf16(aw1[0][ks], bf1, acc1[0][1], 0, 0, 0);
      acc1[1][0] = __builtin_amdgcn_mfma_f32_16x16x32_bf16(aw1[1][ks], bf0, acc1[1][0], 0, 0, 0);
      acc1[1][1] = __builtin_amdgcn_mfma_f32_16x16x32_bf16(aw1[1][ks], bf1, acc1[1][1], 0, 0, 0);
      acc2[0][0] = __builtin_amdgcn_mfma_f32_16x16x32_bf16(aw2[0][ks], bf0, acc2[0][0], 0, 0, 0);
      acc2[0][1] = __builtin_amdgcn_mfma_f32_16x16x32_bf16(aw2[0][ks], bf1, acc2[0][1], 0, 0, 0);
      acc2[1][0] = __builtin_amdgcn_mfma_f32_16x16x32_bf16(aw2[1][ks], bf0, acc2[1][0], 0, 0, 0);
      acc2[1][1] = __builtin_amdgcn_mfma_f32_16x16x32_bf16(aw2[1][ks], bf1, acc2[1][1], 0, 0, 0);
    }

    // epilogue: GLU + bn, store 16 f32 per lane
    int p0 = pbase + pt * 32;
    #pragma unroll
    for (int mi = 0; mi < 2; ++mi)
      #pragma unroll
      for (int r = 0; r < 4; ++r) {
        int o = ow0 + mi * 16 + lgr * 4 + r;
        float* gp = g2 + ((size_t)b * 256 + o) * 800 + p0 + lrow;
        #pragma unroll
        for (int nf = 0; nf < 2; ++nf) {
          float a = acc1[mi][nf][r] + b1v[mi][r];
          float g = acc2[mi][nf][r] + b2v[mi][r];
          float sig = 1.f / (1.f + __expf(-g));
          gp[nf * 16] = (a * sig) * scv[mi][r] + shv[mi][r];
        }
      }
    __syncthreads();  // all x_l reads done before next overwrite
  }
}

// ---------------------------------------------------------------- launch
extern "C" void kernel_launch(void* const* d_in, const int* in_sizes, int n_in,
                              void* d_out, int out_size, void* d_ws, size_t ws_size,
                              hipStream_t stream) {
  (void)in_sizes; (void)n_in; (void)out_size; (void)ws_size;
  const float* g1    = (const float*)d_in[0];
  const float* h2    = (const float*)d_in[1];
  const float* As_r  = (const float*)d_in[2];
  const float* At_r  = (const float*)d_in[3];
  const float* sc1_w = (const float*)d_in[4];
  const float* sc1_b = (const float*)d_in[5];
  const float* sc2_w = (const float*)d_in[6];
  const float* sc2_b = (const float*)d_in[7];
  const float* tc1_w = (const float*)d_in[8];
  const float* tc1_b = (const float*)d_in[9];
  const float* tc2_w = (const float*)d_in[10];
  const float* tc2_b = (const float*)d_in[11];
  const float* act_s = (const float*)d_in[12];
  const float* act_t = (const float*)d_in[13];
  const float* sp_w  = (const float*)d_in[14];
  const float* sp_b  = (const float*)d_in[15];
  const float* sp_gamma = (const float*)d_in[16];
  const float* sp_beta  = (const float*)d_in[17];
  const float* sp_mean  = (const float*)d_in[18];
  const float* sp_var   = (const float*)d_in[19];
  const float* W1_w = (const float*)d_in[20];
  const float* W1_b = (const float*)d_in[21];
  const float* W2_w = (const float*)d_in[22];
  const float* W2_b = (const float*)d_in[23];
  const float* bn_gamma = (const float*)d_in[24];
  const float* bn_beta  = (const float*)d_in[25];
  const float* bn_mean  = (const float*)d_in[26];
  const float* bn_var   = (const float*)d_in[27];

  float* out = (float*)d_out;
  float* out_g2     = out;
  float* out_As_at  = out + 26214400;
  float* out_At_at  = out + 26294400;
  float* out_As_act = out + 26818688;
  float* out_At_act = out + 26898688;

  char* ws = (char*)d_ws;
  float* sf    = (float*)(ws + 0);
  float* tf    = (float*)(ws + 1638400);
  float* As_ws = (float*)(ws + 5832704);
  float* Atev  = (float*)(ws + 6152704);
  unsigned short* Wc1 = (unsigned short*)(ws + 7201280);
  unsigned short* Wc2 = (unsigned short*)(ws + 7332352);
  float* b1pv  = (float*)(ws + 7463424);
  float* b2pv  = (float*)(ws + 7464448);
  float* bnscv = (float*)(ws + 7465472);
  float* bnshv = (float*)(ws + 7466496);
  unsigned short* g1vt = (unsigned short*)(ws + 7467520);
  unsigned short* nu2  = (unsigned short*)(ws + 59896320);

  k_means_tr<<<dim3(16384), dim3(256), 0, stream>>>(g1, sf, tf, g1vt);
  k_spat<<<dim3(128), dim3(256), 0, stream>>>(sf, sc1_w, sc1_b, sc2_w, sc2_b,
                                              As_r, act_s, As_ws, out_As_at, out_As_act);
  k_temp<<<dim3(128), dim3(256), 0, stream>>>(tf, tc1_w, tc1_b, tc2_w, tc2_b,
                                              At_r, act_t, Atev, out_At_at, out_At_act);
  k_prep<<<dim3(256), dim3(256), 0, stream>>>(W1_w, W1_b, W2_w, W2_b, sp_w, sp_b,
                                              sp_gamma, sp_beta, sp_mean, sp_var,
                                              bn_gamma, bn_beta, bn_mean, bn_var,
                                              Wc1, Wc2, b1pv, b2pv, bnscv, bnshv);
  k_nu2<<<dim3(2048), dim3(256), 0, stream>>>(g1vt, Atev, As_ws, nu2);
  k_final<<<dim3(640), dim3(512), 0, stream>>>(nu2, h2, Wc1, Wc2, b1pv, b2pv,
                                               bnscv, bnshv, out_g2);
}

// Round 2
// 377.524 us; speedup vs baseline: 1.4525x; 1.0798x over previous
//
#include <hip/hip_runtime.h>
#include <cstdint>
#include <cstddef>

typedef __attribute__((ext_vector_type(8))) short short8;
typedef __attribute__((ext_vector_type(4))) float f32x4;

#define EPSF 1e-5f

__device__ __forceinline__ unsigned short f2bf(float f) {
  union { float f; unsigned u; } v; v.f = f;
  unsigned r = v.u + 0x7FFFu + ((v.u >> 16) & 1u);
  return (unsigned short)(r >> 16);
}

// ---------------------------------------------------------------- kernel A
// per (b,c): sf = mean_t, tf = mean_v, and g1vt[b][c][v][t] = bf16(g1[b][c][t][v])
__global__ __launch_bounds__(256) void k_means_tr(
    const float* __restrict__ g1, float* __restrict__ sf, float* __restrict__ tf,
    unsigned short* __restrict__ g1vt) {
  __shared__ __align__(16) float tile[1600];
  int bc = blockIdx.x;
  const float4* src = (const float4*)(g1 + (size_t)bc * 1600);
  float4* dst = (float4*)tile;
  for (int i = threadIdx.x; i < 400; i += 256) dst[i] = src[i];
  __syncthreads();
  int t = threadIdx.x;
  if (t < 64) {
    float s = 0.f;
    #pragma unroll
    for (int v = 0; v < 25; ++v) s += tile[t * 25 + v];
    tf[(size_t)bc * 64 + t] = s * (1.f / 25.f);
  } else if (t < 89) {
    int v = t - 64;
    float s = 0.f;
    for (int tt = 0; tt < 64; ++tt) s += tile[tt * 25 + v];
    sf[(size_t)bc * 25 + v] = s * (1.f / 64.f);
  }
  for (int p = threadIdx.x; p < 800; p += 256) {
    int j = p * 2;
    int v = j >> 6, tt = j & 63;
    unsigned short lo = f2bf(tile[tt * 25 + v]);
    unsigned short hi = f2bf(tile[(tt + 1) * 25 + v]);
    unsigned pack = (unsigned)lo | ((unsigned)hi << 16);
    *((unsigned*)(g1vt + (size_t)bc * 1600 + j)) = pack;
  }
}

// ---------------------------------------------------------------- kernel S (fused spat + temp + prep)
// blk<128: spatial attn (b=blk); blk<256: temporal attn (b=blk-128); else: W-fold prep (o=blk-256)
__global__ __launch_bounds__(256) void k_small(
    const float* __restrict__ sf, const float* __restrict__ tf,
    const float* __restrict__ sc1_w, const float* __restrict__ sc1_b,
    const float* __restrict__ sc2_w, const float* __restrict__ sc2_b,
    const float* __restrict__ tc1_w, const float* __restrict__ tc1_b,
    const float* __restrict__ tc2_w, const float* __restrict__ tc2_b,
    const float* __restrict__ As_r, const float* __restrict__ act_s,
    const float* __restrict__ At_r, const float* __restrict__ act_t,
    const float* __restrict__ W1_w, const float* __restrict__ W1_b,
    const float* __restrict__ W2_w, const float* __restrict__ W2_b,
    const float* __restrict__ sp_w, const float* __restrict__ sp_b,
    const float* __restrict__ sp_gamma, const float* __restrict__ sp_beta,
    const float* __restrict__ sp_mean, const float* __restrict__ sp_var,
    const float* __restrict__ bn_gamma, const float* __restrict__ bn_beta,
    const float* __restrict__ bn_mean, const float* __restrict__ bn_var,
    unsigned short* __restrict__ As_bf, unsigned short* __restrict__ At_bf,
    float* __restrict__ out_As_at, float* __restrict__ out_As_act,
    float* __restrict__ out_At_at, float* __restrict__ out_At_act,
    unsigned short* __restrict__ Wc1, unsigned short* __restrict__ Wc2,
    float* __restrict__ b1p, float* __restrict__ b2p,
    float* __restrict__ bnsc, float* __restrict__ bnsh) {
  __shared__ __align__(16) float sm[14336];  // 56 KiB union
  int blk = blockIdx.x;
  int tid = threadIdx.x;

  if (blk < 128) {
    // ---------------- spatial attention
    int b = blk;
    float* sfl = sm;          // 3200
    float* w1  = sm + 3200;   // 2048
    float* w2  = sm + 5248;   // 2048
    float* s1  = sm + 7296;   // 400
    float* s2  = sm + 7696;   // 400
    for (int i = tid; i < 3200; i += 256) sfl[i] = sf[(size_t)b * 3200 + i];
    for (int i = tid; i < 2048; i += 256) { w1[i] = sc1_w[i]; w2[i] = sc2_w[i]; }
    __syncthreads();
    for (int i = tid; i < 800; i += 256) {
      if (i < 400) {
        int v = i >> 4, r = i & 15;
        float s = sc1_b[r];
        for (int c = 0; c < 128; ++c) s += w1[r * 128 + c] * sfl[c * 25 + v];
        s1[v * 16 + r] = s;
      } else {
        int j = i - 400;
        int r = j / 25, u = j % 25;
        float s = sc2_b[r];
        for (int c = 0; c < 128; ++c) s += w2[r * 128 + c] * sfl[c * 25 + u];
        s2[r * 25 + u] = s;
      }
    }
    __syncthreads();
    // padded bf16 output [32][40]; interior [v<25][u<25]
    for (int i = tid; i < 1280; i += 256) {
      int v = i / 40, u = i % 40;
      if (v < 25 && u < 25) {
        int ii = v * 25 + u;
        float d = 0.f;
        #pragma unroll
        for (int r = 0; r < 16; ++r) d += s1[v * 16 + r] * s2[r * 25 + u];
        float at = d > 0.f ? tanhf(d) : 0.f;
        float act = As_r[(size_t)b * 625 + ii] * act_s[ii];
        out_As_at[(size_t)b * 625 + ii] = at;
        out_As_act[(size_t)b * 625 + ii] = act;
        As_bf[(size_t)b * 1280 + i] = f2bf(at + act);
      } else {
        As_bf[(size_t)b * 1280 + i] = 0;
      }
    }
  } else if (blk < 256) {
    // ---------------- temporal attention
    int b = blk - 128;
    float* tfl = sm;           // 8192
    float* w1  = sm + 8192;    // 2048
    float* w2  = sm + 10240;   // 2048
    float* t1  = sm + 12288;   // 1024
    float* t2  = sm + 13312;   // 1024
    for (int i = tid; i < 8192; i += 256) tfl[i] = tf[(size_t)b * 8192 + i];
    for (int i = tid; i < 2048; i += 256) { w1[i] = tc1_w[i]; w2[i] = tc2_w[i]; }
    __syncthreads();
    for (int i = tid; i < 2048; i += 256) {
      if (i < 1024) {
        int t = i >> 4, r = i & 15;
        float s = tc1_b[r];
        for (int c = 0; c < 128; ++c) s += w1[r * 128 + c] * tfl[c * 64 + t];
        t1[t * 16 + r] = s;
      } else {
        int j = i - 1024;
        int r = j >> 6, t = j & 63;
        float s = tc2_b[r];
        for (int c = 0; c < 128; ++c) s += w2[r * 128 + c] * tfl[c * 64 + t];
        t2[r * 64 + t] = s;
      }
    }
    __syncthreads();
    for (int i = tid; i < 4096; i += 256) {
      int t = i >> 6, y = i & 63;
      float d = 0.f;
      #pragma unroll
      for (int r = 0; r < 16; ++r) d += t1[t * 16 + r] * t2[r * 64 + y];
      float at = d > 0.f ? tanhf(d) : 0.f;
      float act = At_r[(size_t)b * 4096 + i] * act_t[i];
      out_At_at[(size_t)b * 4096 + i] = at;
      out_At_act[(size_t)b * 4096 + i] = act;
      if ((y & 1) == 0)
        At_bf[(size_t)b * 2304 + (y >> 1) * 72 + t] = f2bf(at + act);  // [y/2][t] pitch 72
    }
    // zero the pad columns t=64..71 (copied to LDS, never consumed as data)
    for (int i = tid; i < 256; i += 256)
      At_bf[(size_t)b * 2304 + (i >> 3) * 72 + 64 + (i & 7)] = 0;
  } else {
    // ---------------- fold sp+bn into W1/W2
    int o = blk - 256;
    float* w1row = sm;         // 256
    float* w2row = sm + 256;   // 256
    float* scale = sm + 512;   // 128
    float* shift = sm + 640;   // 128
    int t = tid;
    w1row[t] = W1_w[o * 256 + t];
    w2row[t] = W2_w[o * 256 + t];
    if (t < 128) {
      float sc = sp_gamma[t] * rsqrtf(sp_var[t] + EPSF);
      scale[t] = sc;
      shift[t] = (sp_b[t] - sp_mean[t]) * sc + sp_beta[t];
    }
    __syncthreads();
    if (t < 128) {
      float a1 = 0.f, a2 = 0.f;
      for (int c = 0; c < 128; ++c) {
        float sw = sp_w[c * 128 + t];
        a1 += w1row[c] * scale[c] * sw;
        a2 += w2row[c] * scale[c] * sw;
      }
      Wc1[o * 256 + t] = f2bf(a1);
      Wc2[o * 256 + t] = f2bf(a2);
    } else {
      Wc1[o * 256 + t] = f2bf(w1row[t]);
      Wc2[o * 256 + t] = f2bf(w2row[t]);
    }
    if (t == 0) {
      float s = 0.f;
      for (int c = 0; c < 128; ++c) s += w1row[c] * shift[c];
      b1p[o] = W1_b[o] + s;
      float bs = bn_gamma[o] * rsqrtf(bn_var[o] + EPSF);
      bnsc[o] = bs;
      bnsh[o] = bn_beta[o] - bn_mean[o] * bs;
    } else if (t == 1) {
      float s = 0.f;
      for (int c = 0; c < 128; ++c) s += w2row[c] * shift[c];
      b2p[o] = W2_b[o] + s;
    }
  }
}

// ---------------------------------------------------------------- kernel N (nu2 via 2-stage MFMA)
// per block: b, 8 channels. stage1: P2[y][(c,v)] = At_ev @ g1vt; stage2: nu2[c][y][u] = P2 @ As^T
// At_bf / As_bf arrive pre-converted + pre-padded from k_small → staging is a straight u32 copy.
__global__ __launch_bounds__(256) void k_nu2(
    const unsigned short* __restrict__ g1vt, const unsigned short* __restrict__ At_bf,
    const unsigned short* __restrict__ As_bf, unsigned short* __restrict__ nu2) {
  __shared__ __align__(16) unsigned short At_l[32 * 72];   // [y][t] pad 72
  __shared__ __align__(16) unsigned short As_l[32 * 40];   // [u][v] pad 40, zero-padded
  __shared__ __align__(16) unsigned short P2_l[8 * 32 * 40]; // [c][y][v] pad 40
  int blk = blockIdx.x;
  int b = blk >> 4;
  int c0 = (blk & 15) * 8;
  int tid = threadIdx.x;
  int w = tid >> 6, l = tid & 63;
  {
    const unsigned* Atg = (const unsigned*)(At_bf + (size_t)b * 2304);
    const unsigned* Asg = (const unsigned*)(As_bf + (size_t)b * 1280);
    unsigned* Atl = (unsigned*)At_l;
    unsigned* Asl = (unsigned*)As_l;
    unsigned* P2u = (unsigned*)P2_l;
    for (int i = tid; i < 1152; i += 256) Atl[i] = Atg[i];
    for (int i = tid; i < 640; i += 256) Asl[i] = Asg[i];
    for (int i = tid; i < 5120; i += 256) P2u[i] = 0;
  }
  __syncthreads();

  // stage 1: A-frags (At) preloaded
  short8 afr[2][2];
  #pragma unroll
  for (int mi = 0; mi < 2; ++mi)
    #pragma unroll
    for (int ks = 0; ks < 2; ++ks) {
      int y = mi * 16 + (l & 15);
      int tt = ks * 32 + (l >> 4) * 8;
      afr[mi][ks] = *(const short8*)(At_l + y * 72 + tt);
    }
  for (int nt = w; nt < 13; nt += 4) {
    int n = nt * 16 + (l & 15);
    int nc = n < 200 ? n : 199;
    int cc = nc / 25, vv = nc % 25;
    const unsigned short* gp = g1vt + ((size_t)(b * 128 + c0 + cc) * 25 + vv) * 64;
    short8 bfr[2];
    #pragma unroll
    for (int ks = 0; ks < 2; ++ks)
      bfr[ks] = *(const short8*)(gp + ks * 32 + (l >> 4) * 8);
    #pragma unroll
    for (int mi = 0; mi < 2; ++mi) {
      f32x4 acc = {0.f, 0.f, 0.f, 0.f};
      acc = __builtin_amdgcn_mfma_f32_16x16x32_bf16(afr[mi][0], bfr[0], acc, 0, 0, 0);
      acc = __builtin_amdgcn_mfma_f32_16x16x32_bf16(afr[mi][1], bfr[1], acc, 0, 0, 0);
      if (n < 200) {
        #pragma unroll
        for (int r = 0; r < 4; ++r) {
          int y = mi * 16 + (l >> 4) * 4 + r;
          P2_l[cc * 1280 + y * 40 + vv] = f2bf(acc[r]);
        }
      }
    }
  }
  __syncthreads();

  // stage 2
  for (int cw = w; cw < 8; cw += 4) {
    #pragma unroll
    for (int mi = 0; mi < 2; ++mi) {
      int y = mi * 16 + (l & 15);
      short8 a2 = *(const short8*)(P2_l + cw * 1280 + y * 40 + (l >> 4) * 8);
      #pragma unroll
      for (int nt2 = 0; nt2 < 2; ++nt2) {
        int u = nt2 * 16 + (l & 15);
        short8 b2 = *(const short8*)(As_l + u * 40 + (l >> 4) * 8);
        f32x4 acc = {0.f, 0.f, 0.f, 0.f};
        acc = __builtin_amdgcn_mfma_f32_16x16x32_bf16(a2, b2, acc, 0, 0, 0);
        #pragma unroll
        for (int r = 0; r < 4; ++r) {
          int yy = mi * 16 + (l >> 4) * 4 + r;
          int uu = nt2 * 16 + (l & 15);
          if (uu < 25)
            nu2[(size_t)(b * 128 + c0 + cw) * 800 + yy * 25 + uu] = f2bf(acc[r]);
        }
      }
    }
  }
}

// ---------------------------------------------------------------- kernel F (final GLU GEMM + bn)
// v3: double-buffered LDS (1 barrier/subtile) + XOR bank swizzle (k ^= p&24) on the [p][k] tile.
// 512 threads / 8 waves; wave w owns o-rows [32w,32w+32), weights in registers; 5 subtiles of 32 p.
__global__ __launch_bounds__(512) void k_final(
    const unsigned short* __restrict__ nu2, const float* __restrict__ h2,
    const unsigned short* __restrict__ Wc1, const unsigned short* __restrict__ Wc2,
    const float* __restrict__ b1p, const float* __restrict__ b2p,
    const float* __restrict__ bnsc, const float* __restrict__ bnsh,
    float* __restrict__ g2) {
  __shared__ __align__(16) unsigned short x_l[2][32 * 264];
  int blk = blockIdx.x;
  int b = blk / 5;
  int pbase = (blk % 5) * 160;
  int tid = threadIdx.x;
  int w = tid >> 6, l = tid & 63;
  int lrow = l & 15, lgr = l >> 4;
  int ow0 = w * 32;

  // ---- weights into registers: 2 mi x 8 ks x 2 mats = 32 short8 = 128 VGPR
  short8 aw1[2][8], aw2[2][8];
  {
    const unsigned short* wr1 = Wc1 + (ow0 + lrow) * 256 + lgr * 8;
    const unsigned short* wr2 = Wc2 + (ow0 + lrow) * 256 + lgr * 8;
    #pragma unroll
    for (int mi = 0; mi < 2; ++mi)
      #pragma unroll
      for (int ks = 0; ks < 8; ++ks) {
        aw1[mi][ks] = *(const short8*)(wr1 + mi * 16 * 256 + ks * 32);
        aw2[mi][ks] = *(const short8*)(wr2 + mi * 16 * 256 + ks * 32);
      }
  }
  // ---- per-lane epilogue constants
  float b1v[2][4], b2v[2][4], scv[2][4], shv[2][4];
  #pragma unroll
  for (int mi = 0; mi < 2; ++mi)
    #pragma unroll
    for (int r = 0; r < 4; ++r) {
      int o = ow0 + mi * 16 + lgr * 4 + r;
      b1v[mi][r] = b1p[o];
      b2v[mi][r] = b2p[o];
      scv[mi][r] = bnsc[o];
      shv[mi][r] = bnsh[o];
    }

  // staging: thread owns one nu2 chunk (8 bf16, row kA) and one h2 chunk (8 f32, row kA)
  int kA = tid >> 2;        // 0..127
  int pA = (tid & 3) * 8;   // 0,8,16,24  (rows pA..pA+7 share p&24 == pA)
  int kswA = kA ^ pA;       // XOR bank swizzle, write side
  const unsigned short* srcA = nu2 + ((size_t)b * 128 + kA) * 800 + pbase + pA;
  const float* srcB = h2 + ((size_t)b * 128 + kA) * 800 + pbase + pA;

  short8 cA;
  float4 cB0, cB1;
  cA = *(const short8*)srcA;
  cB0 = *(const float4*)srcB;
  cB1 = *(const float4*)(srcB + 4);
  // prologue: subtile 0 -> buf 0
  {
    unsigned short* xb = x_l[0];
    #pragma unroll
    for (int j = 0; j < 8; ++j)
      xb[(pA + j) * 264 + kswA] = (unsigned short)cA[j];
    xb[(pA + 0) * 264 + 128 + kswA] = f2bf(cB0.x);
    xb[(pA + 1) * 264 + 128 + kswA] = f2bf(cB0.y);
    xb[(pA + 2) * 264 + 128 + kswA] = f2bf(cB0.z);
    xb[(pA + 3) * 264 + 128 + kswA] = f2bf(cB0.w);
    xb[(pA + 4) * 264 + 128 + kswA] = f2bf(cB1.x);
    xb[(pA + 5) * 264 + 128 + kswA] = f2bf(cB1.y);
    xb[(pA + 6) * 264 + 128 + kswA] = f2bf(cB1.z);
    xb[(pA + 7) * 264 + 128 + kswA] = f2bf(cB1.w);
  }

  int sw0 = lrow & 8;        // read swizzle rows 0..15
  int sw1 = 16 | sw0;        // read swizzle rows 16..31

  for (int pt = 0; pt < 5; ++pt) {
    __syncthreads();  // buf[pt&1] fully staged

    // T14: issue next subtile's global loads; latency hides under MFMA below
    if (pt < 4) {
      cA = *(const short8*)(srcA + (pt + 1) * 32);
      cB0 = *(const float4*)(srcB + (pt + 1) * 32);
      cB1 = *(const float4*)(srcB + (pt + 1) * 32 + 4);
    }

    const unsigned short* xb = x_l[pt & 1];
    f32x4 vz = {0.f, 0.f, 0.f, 0.f};
    f32x4 acc1[2][2], acc2[2][2];
    #pragma unroll
    for (int mi = 0; mi < 2; ++mi)
      #pragma unroll
      for (int nf = 0; nf < 2; ++nf) { acc1[mi][nf] = vz; acc2[mi][nf] = vz; }
    #pragma unroll
    for (int ks = 0; ks < 8; ++ks) {
      int koff = ks * 32 + lgr * 8;
      short8 bf0 = *(const short8*)(xb + lrow * 264 + (koff ^ sw0));
      short8 bf1 = *(const short8*)(xb + (16 + lrow) * 264 + (koff ^ sw1));
      acc1[0][0] = __builtin_amdgcn_mfma_f32_16x16x32_bf16(aw1[0][ks], bf0, acc1[0][0], 0, 0, 0);
      acc1[0][1] = __builtin_amdgcn_mfma_f32_16x16x32_bf16(aw1[0][ks], bf1, acc1[0][1], 0, 0, 0);
      acc1[1][0] = __builtin_amdgcn_mfma_f32_16x16x32_bf16(aw1[1][ks], bf0, acc1[1][0], 0, 0, 0);
      acc1[1][1] = __builtin_amdgcn_mfma_f32_16x16x32_bf16(aw1[1][ks], bf1, acc1[1][1], 0, 0, 0);
      acc2[0][0] = __builtin_amdgcn_mfma_f32_16x16x32_bf16(aw2[0][ks], bf0, acc2[0][0], 0, 0, 0);
      acc2[0][1] = __builtin_amdgcn_mfma_f32_16x16x32_bf16(aw2[0][ks], bf1, acc2[0][1], 0, 0, 0);
      acc2[1][0] = __builtin_amdgcn_mfma_f32_16x16x32_bf16(aw2[1][ks], bf0, acc2[1][0], 0, 0, 0);
      acc2[1][1] = __builtin_amdgcn_mfma_f32_16x16x32_bf16(aw2[1][ks], bf1, acc2[1][1], 0, 0, 0);
    }

    // stage next subtile into the other buffer (no barrier needed: disjoint buffer)
    if (pt < 4) {
      unsigned short* xn = x_l[(pt + 1) & 1];
      #pragma unroll
      for (int j = 0; j < 8; ++j)
        xn[(pA + j) * 264 + kswA] = (unsigned short)cA[j];
      xn[(pA + 0) * 264 + 128 + kswA] = f2bf(cB0.x);
      xn[(pA + 1) * 264 + 128 + kswA] = f2bf(cB0.y);
      xn[(pA + 2) * 264 + 128 + kswA] = f2bf(cB0.z);
      xn[(pA + 3) * 264 + 128 + kswA] = f2bf(cB0.w);
      xn[(pA + 4) * 264 + 128 + kswA] = f2bf(cB1.x);
      xn[(pA + 5) * 264 + 128 + kswA] = f2bf(cB1.y);
      xn[(pA + 6) * 264 + 128 + kswA] = f2bf(cB1.z);
      xn[(pA + 7) * 264 + 128 + kswA] = f2bf(cB1.w);
    }

    // epilogue: GLU + bn, store 16 f32 per lane (drains while others compute)
    int p0 = pbase + pt * 32;
    #pragma unroll
    for (int mi = 0; mi < 2; ++mi)
      #pragma unroll
      for (int r = 0; r < 4; ++r) {
        float* gp = g2 + ((size_t)b * 256 + ow0 + mi * 16 + lgr * 4 + r) * 800 + p0 + lrow;
        #pragma unroll
        for (int nf = 0; nf < 2; ++nf) {
          float a = acc1[mi][nf][r] + b1v[mi][r];
          float g = acc2[mi][nf][r] + b2v[mi][r];
          float sig = 1.f / (1.f + __expf(-g));
          gp[nf * 16] = (a * sig) * scv[mi][r] + shv[mi][r];
        }
      }
  }
}

// ---------------------------------------------------------------- launch
extern "C" void kernel_launch(void* const* d_in, const int* in_sizes, int n_in,
                              void* d_out, int out_size, void* d_ws, size_t ws_size,
                              hipStream_t stream) {
  (void)in_sizes; (void)n_in; (void)out_size; (void)ws_size;
  const float* g1    = (const float*)d_in[0];
  const float* h2    = (const float*)d_in[1];
  const float* As_r  = (const float*)d_in[2];
  const float* At_r  = (const float*)d_in[3];
  const float* sc1_w = (const float*)d_in[4];
  const float* sc1_b = (const float*)d_in[5];
  const float* sc2_w = (const float*)d_in[6];
  const float* sc2_b = (const float*)d_in[7];
  const float* tc1_w = (const float*)d_in[8];
  const float* tc1_b = (const float*)d_in[9];
  const float* tc2_w = (const float*)d_in[10];
  const float* tc2_b = (const float*)d_in[11];
  const float* act_s = (const float*)d_in[12];
  const float* act_t = (const float*)d_in[13];
  const float* sp_w  = (const float*)d_in[14];
  const float* sp_b  = (const float*)d_in[15];
  const float* sp_gamma = (const float*)d_in[16];
  const float* sp_beta  = (const float*)d_in[17];
  const float* sp_mean  = (const float*)d_in[18];
  const float* sp_var   = (const float*)d_in[19];
  const float* W1_w = (const float*)d_in[20];
  const float* W1_b = (const float*)d_in[21];
  const float* W2_w = (const float*)d_in[22];
  const float* W2_b = (const float*)d_in[23];
  const float* bn_gamma = (const float*)d_in[24];
  const float* bn_beta  = (const float*)d_in[25];
  const float* bn_mean  = (const float*)d_in[26];
  const float* bn_var   = (const float*)d_in[27];

  float* out = (float*)d_out;
  float* out_g2     = out;
  float* out_As_at  = out + 26214400;
  float* out_At_at  = out + 26294400;
  float* out_As_act = out + 26818688;
  float* out_At_act = out + 26898688;

  char* ws = (char*)d_ws;
  float* sf    = (float*)(ws + 0);
  float* tf    = (float*)(ws + 1638400);
  unsigned short* As_bf = (unsigned short*)(ws + 5832704);  // 128*1280*2 = 327680
  unsigned short* At_bf = (unsigned short*)(ws + 6160384);  // 128*2304*2 = 589824
  unsigned short* Wc1 = (unsigned short*)(ws + 7201280);
  unsigned short* Wc2 = (unsigned short*)(ws + 7332352);
  float* b1pv  = (float*)(ws + 7463424);
  float* b2pv  = (float*)(ws + 7464448);
  float* bnscv = (float*)(ws + 7465472);
  float* bnshv = (float*)(ws + 7466496);
  unsigned short* g1vt = (unsigned short*)(ws + 7467520);
  unsigned short* nu2  = (unsigned short*)(ws + 59896320);

  k_means_tr<<<dim3(16384), dim3(256), 0, stream>>>(g1, sf, tf, g1vt);
  k_small<<<dim3(512), dim3(256), 0, stream>>>(sf, tf, sc1_w, sc1_b, sc2_w, sc2_b,
                                               tc1_w, tc1_b, tc2_w, tc2_b,
                                               As_r, act_s, At_r, act_t,
                                               W1_w, W1_b, W2_w, W2_b, sp_w, sp_b,
                                               sp_gamma, sp_beta, sp_mean, sp_var,
                                               bn_gamma, bn_beta, bn_mean, bn_var,
                                               As_bf, At_bf, out_As_at, out_As_act,
                                               out_At_at, out_At_act,
                                               Wc1, Wc2, b1pv, b2pv, bnscv, bnshv);
  k_nu2<<<dim3(2048), dim3(256), 0, stream>>>(g1vt, At_bf, As_bf, nu2);
  k_final<<<dim3(640), dim3(512), 0, stream>>>(nu2, h2, Wc1, Wc2, b1pv, b2pv,
                                               bnscv, bnshv, out_g2);
}